// Round 4
// baseline (270.760 us; speedup 1.0000x reference)
//
#include <hip/hip_runtime.h>
#include <hip/hip_bf16.h>
#include <math.h>

// Problem constants
#define BATCH 32
#define CIN   256
#define HIN   28
#define WIN   28
#define NPROT 1024
#define HOUT  26
#define WOUT  26
#define MTOT  (BATCH*HOUT*WOUT)   // 21632 = 169*128
#define HWIN  (HIN*WIN)           // 784
#define KTOT  (CIN*9)             // 2304
#define NKT   72                  // K-tiles of 32: 9 taps x 8 chunks

typedef __attribute__((ext_vector_type(8))) short short8;
typedef __attribute__((ext_vector_type(4))) float f32x4;

// ---- workspace layout (bytes) ----
// xT  : [32][784][256] bf16  = 12,845,056
// pTT : [9][1024][256] bf16  =  4,718,592
// s   : [32*784] f32         =    100,352
// psq : [1024] f32           =      4,096
#define OFF_XT  ((size_t)0)
#define OFF_PTT ((size_t)12845056)
#define OFF_S   ((size_t)17563648)
#define OFF_PSQ ((size_t)17664000)
#define WS_NEED ((size_t)17668096)

__device__ __forceinline__ void gload16(const void* g, void* l) {
    // async global->LDS, 16B per lane; LDS dest is wave-uniform base + lane*16
    __builtin_amdgcn_global_load_lds((__attribute__((address_space(1))) void*)g,
                                     (__attribute__((address_space(3))) void*)l,
                                     16, 0, 0);
}

// ---- P1: x NCHW fp32 -> NHWC bf16, plus per-pixel sum of squares (no atomics) ----
__global__ void xpose_kernel(const float* __restrict__ x,
                             __hip_bfloat16* __restrict__ xT,
                             float* __restrict__ s) {
    __shared__ float tile[32][33];
    const int b = blockIdx.z, hw0 = blockIdx.x * 32;
    const int tx = threadIdx.x, ty = threadIdx.y;  // block (32,8)
    const float* xb = x + (size_t)b * CIN * HWIN;
    float ssacc = 0.f;
    for (int cg = 0; cg < 8; ++cg) {
        const int c0 = cg * 32;
        __syncthreads();
        for (int q = 0; q < 4; ++q) {
            int c = c0 + ty + q * 8, hw = hw0 + tx;
            float v = (hw < HWIN) ? xb[c * HWIN + hw] : 0.f;
            tile[ty + q * 8][tx] = v;
        }
        __syncthreads();
        for (int rq = 0; rq < 4; ++rq) {
            float v = tile[ty + rq * 8][tx];
            ssacc += v * v;   // partial over rows {ty, ty+8, ty+16, ty+24}
        }
        for (int q = 0; q < 4; ++q) {
            int hw = hw0 + ty + q * 8, c = c0 + tx;
            if (hw < HWIN)
                xT[((size_t)b * HWIN + hw) * CIN + c] = __float2bfloat16(tile[tx][ty + q * 8]);
        }
    }
    __syncthreads();
    tile[ty][tx] = ssacc;
    __syncthreads();
    if (ty == 0) {
        int hw = hw0 + tx;
        if (hw < HWIN) {
            float a = 0.f;
            for (int r = 0; r < 8; ++r) a += tile[r][tx];
            s[b * HWIN + hw] = a;
        }
    }
}

// ---- P2: prototypes OIHW fp32 -> [tap][p][c] bf16, plus ||p||^2 fp32 ----
__global__ void ppose_kernel(const float* __restrict__ proto,
                             __hip_bfloat16* __restrict__ pTT,
                             float* __restrict__ psq) {
    const int p = blockIdx.x, c = threadIdx.x;
    const float* pp = proto + ((size_t)p * CIN + c) * 9;
    float v[9]; float ss = 0.f;
    for (int t = 0; t < 9; ++t) { v[t] = pp[t]; ss += v[t] * v[t]; }
    for (int t = 0; t < 9; ++t)
        pTT[((size_t)t * NPROT + p) * CIN + c] = __float2bfloat16(v[t]);
    for (int o = 32; o > 0; o >>= 1) ss += __shfl_down(ss, o, 64);
    __shared__ float red[4];
    if ((c & 63) == 0) red[c >> 6] = ss;
    __syncthreads();
    if (c == 0) psq[p] = red[0] + red[1] + red[2] + red[3];
}

// ---- G: implicit-GEMM bf16 MFMA, depth-3 COUNTED-vmcnt pipeline.
// D[p][m] = sum_k proto[p][k] * patch[m][k]
// Tile: 128(p) x 128(m) x BK=32. 4 waves (2x2), per-wave 64x64 via 4x4
// 16x16x32 fragments (verified layout, unchanged since round 0).
// LDS: 3 buffers x (A[128][32] + B[128][32]) bf16 = 3 x 16KB = 48KB
//   -> 3 blocks/CU (12 waves/CU, m97's best-occupancy point).
// Pipeline: while computing K-tile kt from buf[kt%3], stage kt+2 into
// buf[(kt+2)%3]. The boundary wait is vmcnt(4): ONLY kt+2's own 4 loads
// remain outstanding; kt+1's (issued during kt-1) are proven landed.
// A tile's loads get ~2 compute phases (~1200cy) to land, covering the
// ~900cy HBM latency that round-3's 2-buffer vmcnt(0) drain exposed.
// Phase granularity: 1 barrier per 16 MFMA (= m201's 8-phase density);
// setprio(1) around the MFMA cluster (T5) exploits wave role diversity.
// LDS rows (64B) XOR-swizzled: row r's 16B chunk c at slot c^(r&3);
// balanced 8 lanes per 16B bank slot on both ds_read_b128 and staging.
__global__ __launch_bounds__(256, 3)
void gemm_kernel(const __hip_bfloat16* __restrict__ xT,
                 const __hip_bfloat16* __restrict__ pTT,
                 const float* __restrict__ s,
                 const float* __restrict__ psq,
                 float* __restrict__ out) {
    __shared__ __hip_bfloat16 lds[3][8192];  // [buf][ A:0..4095 | B:4096..8191 ]
    const int tid = threadIdx.x, wave = tid >> 6, lane = tid & 63;
    const int n0 = blockIdx.x * 128;  // m (image-pos) tile base
    const int m0 = blockIdx.y * 128;  // p tile base
    const int lrow = lane >> 2;                       // 0..15 (4 lanes/row)
    const int lcol = ((lane & 3) ^ (lrow & 3)) * 8;   // pre-swizzled chunk col

    // staging source addresses (element offsets; tap/chunk added per K-tile)
    // call q in {0,1} covers rows q*64 + wave*16 + lrow
    int xbase[2], pbase[2];
#pragma unroll
    for (int q = 0; q < 2; ++q) {
        int rl = q * 64 + wave * 16 + lrow;
        int mm = n0 + rl;
        int bb = mm / 676, rr = mm % 676, ii = rr / WOUT, jj = rr % WOUT;
        xbase[q] = (bb * HWIN + ii * WIN + jj) * CIN + lcol;
        pbase[q] = (m0 + rl) * CIN + lcol;
    }

    // stage K-tile kt into buffer buf: 4 global_load_lds per wave
    auto stage = [&](int kt, int buf) {
        const int tap = kt >> 3, cc = (kt & 7) * 32;
        const __hip_bfloat16* srcP = pTT + (size_t)tap * (NPROT * CIN) + cc;
        const __hip_bfloat16* srcX = xT + ((tap / 3) * WIN + (tap % 3)) * CIN + cc;
        __hip_bfloat16* base = &lds[buf][0];
#pragma unroll
        for (int q = 0; q < 2; ++q) {
            gload16(srcP + pbase[q], base + (q * 64 + wave * 16) * 32);
            gload16(srcX + xbase[q], base + 4096 + (q * 64 + wave * 16) * 32);
        }
    };

    f32x4 acc[4][4];
#pragma unroll
    for (int a = 0; a < 4; ++a)
#pragma unroll
        for (int b = 0; b < 4; ++b) acc[a][b] = (f32x4){0.f, 0.f, 0.f, 0.f};

    const int wr = wave >> 1, wc = wave & 1;   // wave 2x2: wr->p dir, wc->m dir
    const int quad = lane >> 4, l15 = lane & 15;
    const int rsw = l15 & 3;                    // read-side swizzle key

    // prologue: stage tiles 0 and 1; wait for tile 0 only (tile 1 in flight)
    stage(0, 0);
    stage(1, 1);
    asm volatile("s_waitcnt vmcnt(4)" ::: "memory");
    __builtin_amdgcn_s_barrier();

#pragma unroll 3
    for (int kt = 0; kt < NKT; ++kt) {
        const int cb = kt % 3;
        const __hip_bfloat16* A = &lds[cb][0];
        const __hip_bfloat16* B = &lds[cb][4096];

        // ds_reads of current tile first (long-latency, let them fly)
        const int kc = (quad ^ rsw) * 8;   // swizzled 8-elem k-chunk
        short8 af[4], bf[4];
#pragma unroll
        for (int im = 0; im < 4; ++im)
            af[im] = *(const short8*)&A[(wr * 64 + im * 16 + l15) * 32 + kc];
#pragma unroll
        for (int in = 0; in < 4; ++in)
            bf[in] = *(const short8*)&B[(wc * 64 + in * 16 + l15) * 32 + kc];

        // issue next-next tile's staging (lands 2 phases from now)
        const bool st = (kt + 2) < NKT;
        if (st) stage(kt + 2, (kt + 2) % 3);

        __builtin_amdgcn_s_setprio(1);
#pragma unroll
        for (int im = 0; im < 4; ++im)
#pragma unroll
            for (int in = 0; in < 4; ++in)
                acc[im][in] = __builtin_amdgcn_mfma_f32_16x16x32_bf16(
                    af[im], bf[in], acc[im][in], 0, 0, 0);
        __builtin_amdgcn_s_setprio(0);

        if (kt + 1 < NKT) {
            // counted: leave kt+2's 4 loads in flight; kt+1's are landed.
            if (st) asm volatile("s_waitcnt vmcnt(4)" ::: "memory");
            else    asm volatile("s_waitcnt vmcnt(0)" ::: "memory");
            __builtin_amdgcn_s_barrier();
        }
    }

    // epilogue: out[b][p][i][j] = sqrt(clip(s3 - 2C + psq)), s3 = 3x3 box of s
#pragma unroll
    for (int in = 0; in < 4; ++in) {
        int mm = n0 + wc * 64 + in * 16 + l15;
        int bb = mm / 676, rr = mm % 676, ii = rr / WOUT, jj = rr % WOUT;
        const float* sb = s + bb * HWIN + ii * WIN + jj;
        float s3v = 0.f;
#pragma unroll
        for (int di = 0; di < 3; ++di)
#pragma unroll
            for (int dj = 0; dj < 3; ++dj) s3v += sb[di * WIN + dj];
        float* ob = out + (size_t)bb * (NPROT * 676) + rr;
#pragma unroll
        for (int im = 0; im < 4; ++im) {
            int pbase_ = m0 + wr * 64 + im * 16 + quad * 4;
#pragma unroll
            for (int r = 0; r < 4; ++r) {
                int p = pbase_ + r;
                float d2 = s3v - 2.f * acc[im][in][r] + psq[p];
                ob[(size_t)p * 676] = sqrtf(fmaxf(d2, 1e-14f));
            }
        }
    }
}

// ---- fallback (only if ws too small): direct fp32 ----
__global__ void naive_kernel(const float* __restrict__ x,
                             const float* __restrict__ proto,
                             float* __restrict__ out) {
    __shared__ float patch[KTOT];
    int m = blockIdx.x;
    int b = m / 676, rr = m % 676, i = rr / WOUT, j = rr % WOUT;
    int c = threadIdx.x;
    const float* xb = x + (((size_t)b * CIN + c) * HIN + i) * WIN + j;
    for (int t = 0; t < 9; ++t) patch[c * 9 + t] = xb[(t / 3) * WIN + (t % 3)];
    __syncthreads();
    for (int pp = threadIdx.x; pp < NPROT; pp += 256) {
        const float* pr = proto + (size_t)pp * KTOT;
        float acc = 0.f;
        for (int k = 0; k < KTOT; ++k) { float d = patch[k] - pr[k]; acc += d * d; }
        out[((size_t)b * NPROT + pp) * 676 + rr] = sqrtf(fmaxf(acc, 1e-14f));
    }
}

extern "C" void kernel_launch(void* const* d_in, const int* in_sizes, int n_in,
                              void* d_out, int out_size, void* d_ws, size_t ws_size,
                              hipStream_t stream) {
    const float* x = (const float*)d_in[0];
    const float* proto = (const float*)d_in[1];
    float* out = (float*)d_out;

    if (ws_size < WS_NEED) {
        naive_kernel<<<MTOT, 256, 0, stream>>>(x, proto, out);
        return;
    }

    char* ws = (char*)d_ws;
    __hip_bfloat16* xT  = (__hip_bfloat16*)(ws + OFF_XT);
    __hip_bfloat16* pTT = (__hip_bfloat16*)(ws + OFF_PTT);
    float* s   = (float*)(ws + OFF_S);
    float* psq = (float*)(ws + OFF_PSQ);

    xpose_kernel<<<dim3(25, 1, BATCH), dim3(32, 8), 0, stream>>>(x, xT, s);
    ppose_kernel<<<NPROT, 256, 0, stream>>>(proto, pTT, psq);
    gemm_kernel<<<dim3(169, 8), 256, 0, stream>>>(xT, pTT, s, psq, out);
}

// Round 5
// 254.600 us; speedup vs baseline: 1.0635x; 1.0635x over previous
//
#include <hip/hip_runtime.h>
#include <hip/hip_bf16.h>
#include <math.h>

// Problem constants
#define BATCH 32
#define CIN   256
#define HIN   28
#define WIN   28
#define NPROT 1024
#define HOUT  26
#define WOUT  26
#define MTOT  (BATCH*HOUT*WOUT)   // 21632 = 169*128
#define HWIN  (HIN*WIN)           // 784
#define KTOT  (CIN*9)             // 2304
#define NKT   36                  // K-tiles of 64: 9 taps x 4 chunks

typedef __attribute__((ext_vector_type(8))) short short8;
typedef __attribute__((ext_vector_type(16))) float f32x16;

// ---- workspace layout (bytes) ----
// xT  : [32][784][256] bf16  = 12,845,056
// pTT : [9][1024][256] bf16  =  4,718,592
// s   : [32*784] f32         =    100,352
// psq : [1024] f32           =      4,096
#define OFF_XT  ((size_t)0)
#define OFF_PTT ((size_t)12845056)
#define OFF_S   ((size_t)17563648)
#define OFF_PSQ ((size_t)17664000)
#define WS_NEED ((size_t)17668096)

__device__ __forceinline__ void gload16(const void* g, void* l) {
    // async global->LDS, 16B per lane; LDS dest is wave-uniform base + lane*16
    __builtin_amdgcn_global_load_lds((__attribute__((address_space(1))) void*)g,
                                     (__attribute__((address_space(3))) void*)l,
                                     16, 0, 0);
}

// ---- P1: x NCHW fp32 -> NHWC bf16, plus per-pixel sum of squares (no atomics) ----
__global__ void xpose_kernel(const float* __restrict__ x,
                             __hip_bfloat16* __restrict__ xT,
                             float* __restrict__ s) {
    __shared__ float tile[32][33];
    const int b = blockIdx.z, hw0 = blockIdx.x * 32;
    const int tx = threadIdx.x, ty = threadIdx.y;  // block (32,8)
    const float* xb = x + (size_t)b * CIN * HWIN;
    float ssacc = 0.f;
    for (int cg = 0; cg < 8; ++cg) {
        const int c0 = cg * 32;
        __syncthreads();
        for (int q = 0; q < 4; ++q) {
            int c = c0 + ty + q * 8, hw = hw0 + tx;
            float v = (hw < HWIN) ? xb[c * HWIN + hw] : 0.f;
            tile[ty + q * 8][tx] = v;
        }
        __syncthreads();
        for (int rq = 0; rq < 4; ++rq) {
            float v = tile[ty + rq * 8][tx];
            ssacc += v * v;   // partial over rows {ty, ty+8, ty+16, ty+24}
        }
        for (int q = 0; q < 4; ++q) {
            int hw = hw0 + ty + q * 8, c = c0 + tx;
            if (hw < HWIN)
                xT[((size_t)b * HWIN + hw) * CIN + c] = __float2bfloat16(tile[tx][ty + q * 8]);
        }
    }
    __syncthreads();
    tile[ty][tx] = ssacc;
    __syncthreads();
    if (ty == 0) {
        int hw = hw0 + tx;
        if (hw < HWIN) {
            float a = 0.f;
            for (int r = 0; r < 8; ++r) a += tile[r][tx];
            s[b * HWIN + hw] = a;
        }
    }
}

// ---- P2: prototypes OIHW fp32 -> [tap][p][c] bf16, plus ||p||^2 fp32 ----
__global__ void ppose_kernel(const float* __restrict__ proto,
                             __hip_bfloat16* __restrict__ pTT,
                             float* __restrict__ psq) {
    const int p = blockIdx.x, c = threadIdx.x;
    const float* pp = proto + ((size_t)p * CIN + c) * 9;
    float v[9]; float ss = 0.f;
    for (int t = 0; t < 9; ++t) { v[t] = pp[t]; ss += v[t] * v[t]; }
    for (int t = 0; t < 9; ++t)
        pTT[((size_t)t * NPROT + p) * CIN + c] = __float2bfloat16(v[t]);
    for (int o = 32; o > 0; o >>= 1) ss += __shfl_down(ss, o, 64);
    __shared__ float red[4];
    if ((c & 63) == 0) red[c >> 6] = ss;
    __syncthreads();
    if (c == 0) psq[p] = red[0] + red[1] + red[2] + red[3];
}

// ---- G: implicit-GEMM bf16 MFMA (32x32x16), 2-deep issue-early pipeline.
// D[p][m] = sum_k proto[p][k] * patch[m][k]
// Identical structure/staging/swizzle/LDS to the verified round-3 kernel
// (142us, 0 bank conflicts); ONLY the fragment shape changed:
//   16x16x32 4x4 frags (32 MFMA/tile) -> 32x32x16 2x2 frags (16 MFMA/tile).
// 32x32 pipe: 4096 FLOP/cy vs 3378 (m119) => -17% MFMA cycles, half the
// MFMA instruction issue slots, and 128B-contiguous epilogue stores.
// Operand frag (verified m74/m101): row = lane&31, k-chunk = ks*2+(lane>>5).
// C/D: col(m) = lane&31, row(p) = (reg&3) + 8*(reg>>2) + 4*(lane>>5).
// Bank check (8-lane cycle groups): slot = (2ks+h)^(l&7) covers all 8
// bank-groups => conflict-free, same as round 3.
__global__ __launch_bounds__(256, 2)
void gemm_kernel(const __hip_bfloat16* __restrict__ xT,
                 const __hip_bfloat16* __restrict__ pTT,
                 const float* __restrict__ s,
                 const float* __restrict__ psq,
                 float* __restrict__ out) {
    __shared__ __hip_bfloat16 lds[2][16384];  // [buf][ A:0..8191 | B:8192..16383 ]
    const int tid = threadIdx.x, wave = tid >> 6, lane = tid & 63;
    const int n0 = blockIdx.x * 128;  // m (image-pos) tile base
    const int m0 = blockIdx.y * 128;  // p tile base
    const int lrow = lane >> 3;
    const int lcol = ((lane & 7) ^ lrow) * 8;   // pre-swizzled source chunk col

    // staging source addresses (element offsets; tap/chunk added per K-tile)
    int xbase[4], pbase[4];
#pragma unroll
    for (int q = 0; q < 4; ++q) {
        int rl = wave * 32 + q * 8 + lrow;
        int mm = n0 + rl;
        int bb = mm / 676, rr = mm % 676, ii = rr / WOUT, jj = rr % WOUT;
        xbase[q] = (bb * HWIN + ii * WIN + jj) * CIN + lcol;
        pbase[q] = (m0 + rl) * CIN + lcol;
    }

    // stage K-tile kt into buffer buf: 8 global_load_lds per wave
    auto stage = [&](int kt, int buf) {
        const int tap = kt >> 2, cc = (kt & 3) * 64;
        const __hip_bfloat16* srcP = pTT + (size_t)tap * (NPROT * CIN) + cc;
        const __hip_bfloat16* srcX = xT + ((tap / 3) * WIN + (tap % 3)) * CIN + cc;
        __hip_bfloat16* base = &lds[buf][0];
#pragma unroll
        for (int q = 0; q < 4; ++q) {
            gload16(srcP + pbase[q], base + (wave * 32 + q * 8) * 64);
            gload16(srcX + xbase[q], base + 8192 + (wave * 32 + q * 8) * 64);
        }
    };

    f32x16 acc[2][2];
#pragma unroll
    for (int a = 0; a < 2; ++a)
#pragma unroll
        for (int b = 0; b < 2; ++b)
#pragma unroll
            for (int r = 0; r < 16; ++r) acc[a][b][r] = 0.f;

    const int wr = wave >> 1, wc = wave & 1;   // wave 2x2: wr->p dir, wc->m dir
    const int l31 = lane & 31;                 // frag row within 32x32
    const int h = lane >> 5;                   // k-half select
    const int rsw = l31 & 7;                   // read-side swizzle key (=row&7)

    // prologue: stage tile 0, wait, barrier
    stage(0, 0);
    asm volatile("s_waitcnt vmcnt(0)" ::: "memory");
    __builtin_amdgcn_s_barrier();

#pragma unroll 2
    for (int kt = 0; kt < NKT; ++kt) {
        const int cur = kt & 1;
        const bool st = (kt + 1) < NKT;
        if (st) stage(kt + 1, cur ^ 1);      // issue next tile's loads FIRST

        const __hip_bfloat16* A = &lds[cur][0];
        const __hip_bfloat16* B = &lds[cur][8192];
#pragma unroll
        for (int ks = 0; ks < 4; ++ks) {
            const int kc = ((ks * 2 + h) ^ rsw) * 8;  // swizzled 16B chunk
            short8 af[2], bf[2];
#pragma unroll
            for (int im = 0; im < 2; ++im)
                af[im] = *(const short8*)&A[(wr * 64 + im * 32 + l31) * 64 + kc];
#pragma unroll
            for (int in = 0; in < 2; ++in)
                bf[in] = *(const short8*)&B[(wc * 64 + in * 32 + l31) * 64 + kc];
#pragma unroll
            for (int im = 0; im < 2; ++im)
#pragma unroll
                for (int in = 0; in < 2; ++in)
                    acc[im][in] = __builtin_amdgcn_mfma_f32_32x32x16_bf16(
                        af[im], bf[in], acc[im][in], 0, 0, 0);
        }

        if (st) {
            // kt+1's 8 loads were issued before the compute above; by now
            // their latency is covered. Drain them and flip.
            asm volatile("s_waitcnt vmcnt(0)" ::: "memory");
            __builtin_amdgcn_s_barrier();
        }
    }

    // epilogue: out[b][p][i][j] = sqrt(clip(s3 - 2C + psq)), s3 = 3x3 box of s
    // C/D layout: m = col = lane&31 (same for both k-halves), p row per reg.
#pragma unroll
    for (int in = 0; in < 2; ++in) {
        int mm = n0 + wc * 64 + in * 32 + l31;
        int bb = mm / 676, rr = mm % 676, ii = rr / WOUT, jj = rr % WOUT;
        const float* sb = s + bb * HWIN + ii * WIN + jj;
        float s3v = 0.f;
#pragma unroll
        for (int di = 0; di < 3; ++di)
#pragma unroll
            for (int dj = 0; dj < 3; ++dj) s3v += sb[di * WIN + dj];
        float* ob = out + (size_t)bb * (NPROT * 676) + rr;
#pragma unroll
        for (int im = 0; im < 2; ++im) {
            const int prow0 = m0 + wr * 64 + im * 32 + 4 * h;
#pragma unroll
            for (int reg = 0; reg < 16; ++reg) {
                int p = prow0 + (reg & 3) + 8 * (reg >> 2);
                float d2 = s3v - 2.f * acc[im][in][reg] + psq[p];
                ob[(size_t)p * 676] = sqrtf(fmaxf(d2, 1e-14f));
            }
        }
    }
}

// ---- fallback (only if ws too small): direct fp32 ----
__global__ void naive_kernel(const float* __restrict__ x,
                             const float* __restrict__ proto,
                             float* __restrict__ out) {
    __shared__ float patch[KTOT];
    int m = blockIdx.x;
    int b = m / 676, rr = m % 676, i = rr / WOUT, j = rr % WOUT;
    int c = threadIdx.x;
    const float* xb = x + (((size_t)b * CIN + c) * HIN + i) * WIN + j;
    for (int t = 0; t < 9; ++t) patch[c * 9 + t] = xb[(t / 3) * WIN + (t % 3)];
    __syncthreads();
    for (int pp = threadIdx.x; pp < NPROT; pp += 256) {
        const float* pr = proto + (size_t)pp * KTOT;
        float acc = 0.f;
        for (int k = 0; k < KTOT; ++k) { float d = patch[k] - pr[k]; acc += d * d; }
        out[((size_t)b * NPROT + pp) * 676 + rr] = sqrtf(fmaxf(acc, 1e-14f));
    }
}

extern "C" void kernel_launch(void* const* d_in, const int* in_sizes, int n_in,
                              void* d_out, int out_size, void* d_ws, size_t ws_size,
                              hipStream_t stream) {
    const float* x = (const float*)d_in[0];
    const float* proto = (const float*)d_in[1];
    float* out = (float*)d_out;

    if (ws_size < WS_NEED) {
        naive_kernel<<<MTOT, 256, 0, stream>>>(x, proto, out);
        return;
    }

    char* ws = (char*)d_ws;
    __hip_bfloat16* xT  = (__hip_bfloat16*)(ws + OFF_XT);
    __hip_bfloat16* pTT = (__hip_bfloat16*)(ws + OFF_PTT);
    float* s   = (float*)(ws + OFF_S);
    float* psq = (float*)(ws + OFF_PSQ);

    xpose_kernel<<<dim3(25, 1, BATCH), dim3(32, 8), 0, stream>>>(x, xT, s);
    ppose_kernel<<<NPROT, 256, 0, stream>>>(proto, pTT, psq);
    gemm_kernel<<<dim3(169, 8), 256, 0, stream>>>(xT, pTT, s, psq, out);
}

// Round 6
// 250.886 us; speedup vs baseline: 1.0792x; 1.0148x over previous
//
#include <hip/hip_runtime.h>
#include <hip/hip_bf16.h>
#include <math.h>

// Problem constants
#define BATCH 32
#define CIN   256
#define HIN   28
#define WIN   28
#define NPROT 1024
#define HOUT  26
#define WOUT  26
#define MTOT  (BATCH*HOUT*WOUT)   // 21632 = 169*128
#define HWIN  (HIN*WIN)           // 784
#define KTOT  (CIN*9)             // 2304
#define NKT   36                  // K-tiles of 64: 9 taps x 4 chunks

typedef __attribute__((ext_vector_type(8))) short short8;
typedef __attribute__((ext_vector_type(16))) float f32x16;

// ---- workspace layout (bytes) ----
// xT  : [32][784][256] bf16  = 12,845,056
// pTT : [9][1024][256] bf16  =  4,718,592
// s   : [32*784] f32         =    100,352
// psq : [1024] f32           =      4,096
#define OFF_XT  ((size_t)0)
#define OFF_PTT ((size_t)12845056)
#define OFF_S   ((size_t)17563648)
#define OFF_PSQ ((size_t)17664000)
#define WS_NEED ((size_t)17668096)

__device__ __forceinline__ void gload16(const void* g, void* l) {
    // async global->LDS, 16B per lane; LDS dest is wave-uniform base + lane*16
    __builtin_amdgcn_global_load_lds((__attribute__((address_space(1))) void*)g,
                                     (__attribute__((address_space(3))) void*)l,
                                     16, 0, 0);
}

// ---- P1: x NCHW fp32 -> NHWC bf16, plus per-pixel sum of squares (no atomics) ----
__global__ void xpose_kernel(const float* __restrict__ x,
                             __hip_bfloat16* __restrict__ xT,
                             float* __restrict__ s) {
    __shared__ float tile[32][33];
    const int b = blockIdx.z, hw0 = blockIdx.x * 32;
    const int tx = threadIdx.x, ty = threadIdx.y;  // block (32,8)
    const float* xb = x + (size_t)b * CIN * HWIN;
    float ssacc = 0.f;
    for (int cg = 0; cg < 8; ++cg) {
        const int c0 = cg * 32;
        __syncthreads();
        for (int q = 0; q < 4; ++q) {
            int c = c0 + ty + q * 8, hw = hw0 + tx;
            float v = (hw < HWIN) ? xb[c * HWIN + hw] : 0.f;
            tile[ty + q * 8][tx] = v;
        }
        __syncthreads();
        for (int rq = 0; rq < 4; ++rq) {
            float v = tile[ty + rq * 8][tx];
            ssacc += v * v;   // partial over rows {ty, ty+8, ty+16, ty+24}
        }
        for (int q = 0; q < 4; ++q) {
            int hw = hw0 + ty + q * 8, c = c0 + tx;
            if (hw < HWIN)
                xT[((size_t)b * HWIN + hw) * CIN + c] = __float2bfloat16(tile[tx][ty + q * 8]);
        }
    }
    __syncthreads();
    tile[ty][tx] = ssacc;
    __syncthreads();
    if (ty == 0) {
        int hw = hw0 + tx;
        if (hw < HWIN) {
            float a = 0.f;
            for (int r = 0; r < 8; ++r) a += tile[r][tx];
            s[b * HWIN + hw] = a;
        }
    }
}

// ---- P2: prototypes OIHW fp32 -> [tap][p][c] bf16, plus ||p||^2 fp32 ----
__global__ void ppose_kernel(const float* __restrict__ proto,
                             __hip_bfloat16* __restrict__ pTT,
                             float* __restrict__ psq) {
    const int p = blockIdx.x, c = threadIdx.x;
    const float* pp = proto + ((size_t)p * CIN + c) * 9;
    float v[9]; float ss = 0.f;
    for (int t = 0; t < 9; ++t) { v[t] = pp[t]; ss += v[t] * v[t]; }
    for (int t = 0; t < 9; ++t)
        pTT[((size_t)t * NPROT + p) * CIN + c] = __float2bfloat16(v[t]);
    for (int o = 32; o > 0; o >>= 1) ss += __shfl_down(ss, o, 64);
    __shared__ float red[4];
    if ((c & 63) == 0) red[c >> 6] = ss;
    __syncthreads();
    if (c == 0) psq[p] = red[0] + red[1] + red[2] + red[3];
}

// ---- G: implicit-GEMM bf16 MFMA (32x32x16), 2-deep issue-early pipeline.
// D[p][m] = sum_k proto[p][k] * patch[m][k]
// Same as round-5 EXCEPT the LDS swizzle is now two-level:
//   g(row) = (row&7) ^ ((row>>3)&3);  stored slot = granule ^ g(row)
// Round-5's single-level g(row)=row&7 was a measured 4-way bank conflict
// (SQ_LDS_BANK_CONFLICT = 1.246e7 = +4.0 cyc per ds_read_b128): in a
// stride-8 lane service group {c,c+8,c+16,c+24} the key row&7=c is
// constant and the h-bit XOR-by-1 maps the granule set onto itself.
// The (row>>3)&3 term gives those 4 lanes distinct keys 0,1,2,3 while
// remaining constant inside consecutive-8 groups (where row&7 already
// spans all 8 slots). <=2-way under every plausible service grouping,
// i.e. <= round-3's measured-zero pattern.
// Store side: row base per staging call is 8-aligned with (row>>3)&3 = q&3,
// so the pre-swizzled global source column just gains ^(q&3); each 8-lane
// group still reads one contiguous (permuted) 128B chunk => coalescing kept.
// Operand frag (verified m74/m101): row = lane&31, k-granule = ks*2+(lane>>5).
// C/D: col(m) = lane&31, row(p) = (reg&3) + 8*(reg>>2) + 4*(lane>>5).
__global__ __launch_bounds__(256, 2)
void gemm_kernel(const __hip_bfloat16* __restrict__ xT,
                 const __hip_bfloat16* __restrict__ pTT,
                 const float* __restrict__ s,
                 const float* __restrict__ psq,
                 float* __restrict__ out) {
    __shared__ __hip_bfloat16 lds[2][16384];  // [buf][ A:0..8191 | B:8192..16383 ]
    const int tid = threadIdx.x, wave = tid >> 6, lane = tid & 63;
    const int n0 = blockIdx.x * 128;  // m (image-pos) tile base
    const int m0 = blockIdx.y * 128;  // p tile base
    const int lrow = lane >> 3;

    // staging source addresses; column pre-swizzled with the TWO-LEVEL key:
    // row = wave*32 + q*8 + lrow  =>  g(row) = lrow ^ (q&3)
    int xbase[4], pbase[4];
#pragma unroll
    for (int q = 0; q < 4; ++q) {
        const int lcol = ((lane & 7) ^ lrow ^ (q & 3)) * 8;
        int rl = wave * 32 + q * 8 + lrow;
        int mm = n0 + rl;
        int bb = mm / 676, rr = mm % 676, ii = rr / WOUT, jj = rr % WOUT;
        xbase[q] = (bb * HWIN + ii * WIN + jj) * CIN + lcol;
        pbase[q] = (m0 + rl) * CIN + lcol;
    }

    // stage K-tile kt into buffer buf: 8 global_load_lds per wave
    auto stage = [&](int kt, int buf) {
        const int tap = kt >> 2, cc = (kt & 3) * 64;
        const __hip_bfloat16* srcP = pTT + (size_t)tap * (NPROT * CIN) + cc;
        const __hip_bfloat16* srcX = xT + ((tap / 3) * WIN + (tap % 3)) * CIN + cc;
        __hip_bfloat16* base = &lds[buf][0];
#pragma unroll
        for (int q = 0; q < 4; ++q) {
            gload16(srcP + pbase[q], base + (wave * 32 + q * 8) * 64);
            gload16(srcX + xbase[q], base + 8192 + (wave * 32 + q * 8) * 64);
        }
    };

    f32x16 acc[2][2];
#pragma unroll
    for (int a = 0; a < 2; ++a)
#pragma unroll
        for (int b = 0; b < 2; ++b)
#pragma unroll
            for (int r = 0; r < 16; ++r) acc[a][b][r] = 0.f;

    const int wr = wave >> 1, wc = wave & 1;   // wave 2x2: wr->p dir, wc->m dir
    const int l31 = lane & 31;                 // frag row within 32x32
    const int h = lane >> 5;                   // k-half select
    // read-side two-level key: row = (64|32-aligned base) + l31
    //   => g(row) = (l31&7) ^ (l31>>3)   (base contributes 0 to both fields)
    const int rsw = (l31 & 7) ^ (l31 >> 3);

    // prologue: stage tile 0, wait, barrier
    stage(0, 0);
    asm volatile("s_waitcnt vmcnt(0)" ::: "memory");
    __builtin_amdgcn_s_barrier();

#pragma unroll 2
    for (int kt = 0; kt < NKT; ++kt) {
        const int cur = kt & 1;
        const bool st = (kt + 1) < NKT;
        if (st) stage(kt + 1, cur ^ 1);      // issue next tile's loads FIRST

        const __hip_bfloat16* A = &lds[cur][0];
        const __hip_bfloat16* B = &lds[cur][8192];
#pragma unroll
        for (int ks = 0; ks < 4; ++ks) {
            const int kc = ((ks * 2 + h) ^ rsw) * 8;  // swizzled 16B chunk
            short8 af[2], bf[2];
#pragma unroll
            for (int im = 0; im < 2; ++im)
                af[im] = *(const short8*)&A[(wr * 64 + im * 32 + l31) * 64 + kc];
#pragma unroll
            for (int in = 0; in < 2; ++in)
                bf[in] = *(const short8*)&B[(wc * 64 + in * 32 + l31) * 64 + kc];
#pragma unroll
            for (int im = 0; im < 2; ++im)
#pragma unroll
                for (int in = 0; in < 2; ++in)
                    acc[im][in] = __builtin_amdgcn_mfma_f32_32x32x16_bf16(
                        af[im], bf[in], acc[im][in], 0, 0, 0);
        }

        if (st) {
            // kt+1's 8 loads were issued before the compute above; by now
            // their latency is covered. Drain them and flip.
            asm volatile("s_waitcnt vmcnt(0)" ::: "memory");
            __builtin_amdgcn_s_barrier();
        }
    }

    // epilogue: out[b][p][i][j] = sqrt(clip(s3 - 2C + psq)), s3 = 3x3 box of s
    // C/D layout: m = col = lane&31 (same for both k-halves), p row per reg.
#pragma unroll
    for (int in = 0; in < 2; ++in) {
        int mm = n0 + wc * 64 + in * 32 + l31;
        int bb = mm / 676, rr = mm % 676, ii = rr / WOUT, jj = rr % WOUT;
        const float* sb = s + bb * HWIN + ii * WIN + jj;
        float s3v = 0.f;
#pragma unroll
        for (int di = 0; di < 3; ++di)
#pragma unroll
            for (int dj = 0; dj < 3; ++dj) s3v += sb[di * WIN + dj];
        float* ob = out + (size_t)bb * (NPROT * 676) + rr;
#pragma unroll
        for (int im = 0; im < 2; ++im) {
            const int prow0 = m0 + wr * 64 + im * 32 + 4 * h;
#pragma unroll
            for (int reg = 0; reg < 16; ++reg) {
                int p = prow0 + (reg & 3) + 8 * (reg >> 2);
                float d2 = s3v - 2.f * acc[im][in][reg] + psq[p];
                ob[(size_t)p * 676] = sqrtf(fmaxf(d2, 1e-14f));
            }
        }
    }
}

// ---- fallback (only if ws too small): direct fp32 ----
__global__ void naive_kernel(const float* __restrict__ x,
                             const float* __restrict__ proto,
                             float* __restrict__ out) {
    __shared__ float patch[KTOT];
    int m = blockIdx.x;
    int b = m / 676, rr = m % 676, i = rr / WOUT, j = rr % WOUT;
    int c = threadIdx.x;
    const float* xb = x + (((size_t)b * CIN + c) * HIN + i) * WIN + j;
    for (int t = 0; t < 9; ++t) patch[c * 9 + t] = xb[(t / 3) * WIN + (t % 3)];
    __syncthreads();
    for (int pp = threadIdx.x; pp < NPROT; pp += 256) {
        const float* pr = proto + (size_t)pp * KTOT;
        float acc = 0.f;
        for (int k = 0; k < KTOT; ++k) { float d = patch[k] - pr[k]; acc += d * d; }
        out[((size_t)b * NPROT + pp) * 676 + rr] = sqrtf(fmaxf(acc, 1e-14f));
    }
}

extern "C" void kernel_launch(void* const* d_in, const int* in_sizes, int n_in,
                              void* d_out, int out_size, void* d_ws, size_t ws_size,
                              hipStream_t stream) {
    const float* x = (const float*)d_in[0];
    const float* proto = (const float*)d_in[1];
    float* out = (float*)d_out;

    if (ws_size < WS_NEED) {
        naive_kernel<<<MTOT, 256, 0, stream>>>(x, proto, out);
        return;
    }

    char* ws = (char*)d_ws;
    __hip_bfloat16* xT  = (__hip_bfloat16*)(ws + OFF_XT);
    __hip_bfloat16* pTT = (__hip_bfloat16*)(ws + OFF_PTT);
    float* s   = (float*)(ws + OFF_S);
    float* psq = (float*)(ws + OFF_PSQ);

    xpose_kernel<<<dim3(25, 1, BATCH), dim3(32, 8), 0, stream>>>(x, xT, s);
    ppose_kernel<<<NPROT, 256, 0, stream>>>(proto, pTT, psq);
    gemm_kernel<<<dim3(169, 8), 256, 0, stream>>>(xT, pTT, s, psq, out);
}